// Round 1
// baseline (1489.166 us; speedup 1.0000x reference)
//
#include <hip/hip_runtime.h>
#include <hip/hip_bf16.h>
#include <math.h>

#define SEQ  512
#define BSZ  128
#define EMBD 128
#define H4   512
#define HD   128
#define NTAG 7
#define BOSX 4
#define EOSX 5
#define NEGC (-10000.0f)

template<typename T> __device__ __forceinline__ float ldf(const T* p);
template<> __device__ __forceinline__ float ldf<float>(const float* p) { return *p; }
template<> __device__ __forceinline__ float ldf<__hip_bfloat16>(const __hip_bfloat16* p) { return __bfloat162float(*p); }
template<typename T> __device__ __forceinline__ void stf(T* p, float v);
template<> __device__ __forceinline__ void stf<float>(float* p, float v) { *p = v; }
template<> __device__ __forceinline__ void stf<__hip_bfloat16>(__hip_bfloat16* p, float v) { *p = __float2bfloat16(v); }

// One block per (batch, direction) chain. 512 threads: thread j owns gate row j.
// Phase 1: xw[t][j] = dot(emb[sen[t,b]], Wih[j]) + bias[j]  (stored to global ws)
// Phase 2: sequential LSTM recurrence, h broadcast via LDS each step.
template<typename XWT, typename HT>
__global__ __launch_bounds__(512, 2)
void lstm_chain_kernel(const int* __restrict__ sen, const float* __restrict__ emb,
                       const float* __restrict__ Wih_f, const float* __restrict__ Whh_f,
                       const float* __restrict__ b_f,
                       const float* __restrict__ Wih_b, const float* __restrict__ Whh_b,
                       const float* __restrict__ b_b,
                       XWT* __restrict__ xw, HT* __restrict__ hbuf)
{
    const int tid = threadIdx.x;
    const int chain = blockIdx.x;
    const int dir = chain & 1;          // fwd/bwd adjacent: share embedding gathers in L2
    const int b = chain >> 1;
    const float* __restrict__ Wih  = dir ? Wih_b : Wih_f;
    const float* __restrict__ Whh  = dir ? Whh_b : Whh_f;
    const float* __restrict__ bias = dir ? b_b : b_f;

    __shared__ __align__(16) float xs[4][EMBD];
    __shared__ __align__(16) float h_lds[HD];
    __shared__ __align__(16) float gate_lds[H4];

    // ---------------- Phase 1: input projection ----------------
    float4 w[32];                                      // 128 VGPRs of weights
    {
        const float4* wr = (const float4*)(Wih + tid * EMBD);
        #pragma unroll
        for (int k = 0; k < 32; ++k) w[k] = wr[k];
    }
    const float bj = bias[tid];
    XWT* __restrict__ xw_c = xw + (size_t)chain * (SEQ * H4);

    const int trow = tid >> 7;      // 0..3: which of 4 staged timesteps
    const int uu = tid & 127;
    for (int t0 = 0; t0 < SEQ; t0 += 4) {
        const int tok = sen[(t0 + trow) * BSZ + b];
        xs[trow][uu] = emb[(size_t)tok * EMBD + uu];
        __syncthreads();
        #pragma unroll
        for (int i = 0; i < 4; ++i) {
            const float4* xv = (const float4*)xs[i];
            float a0 = 0.f, a1 = 0.f, a2 = 0.f, a3 = 0.f;
            #pragma unroll
            for (int k = 0; k < 32; ++k) {
                const float4 x4 = xv[k];
                a0 += w[k].x * x4.x; a1 += w[k].y * x4.y;
                a2 += w[k].z * x4.z; a3 += w[k].w * x4.w;
            }
            stf(&xw_c[(t0 + i) * H4 + tid], (a0 + a1) + (a2 + a3) + bj);
        }
        __syncthreads();
    }

    // ---------------- Phase 2: recurrence ----------------
    {
        const float4* wr = (const float4*)(Whh + tid * HD);
        #pragma unroll
        for (int k = 0; k < 32; ++k) w[k] = wr[k];
    }
    if (tid < HD) h_lds[tid] = 0.0f;
    float c = 0.0f;
    HT* __restrict__ hb_c = hbuf + (size_t)(dir * BSZ + b) * (SEQ * HD);
    const int gtype = tid >> 7;       // 0:i 1:f 2:g 3:o  (wave-uniform: 128 = 2 waves)
    __syncthreads();

    int t = dir ? (SEQ - 1) : 0;
    const int tstep = dir ? -1 : 1;
    float xwv = ldf(&xw_c[t * H4 + tid]);
    for (int s = 0; s < SEQ; ++s) {
        float xw_pf = 0.0f;                            // prefetch next step's xw
        if (s + 1 < SEQ) xw_pf = ldf(&xw_c[(t + tstep) * H4 + tid]);
        const float4* hv = (const float4*)h_lds;       // uniform-address LDS broadcast
        float a0 = 0.f, a1 = 0.f, a2 = 0.f, a3 = 0.f;
        #pragma unroll
        for (int k = 0; k < 32; ++k) {
            const float4 h4 = hv[k];
            a0 += w[k].x * h4.x; a1 += w[k].y * h4.y;
            a2 += w[k].z * h4.z; a3 += w[k].w * h4.w;
        }
        const float g = (a0 + a1) + (a2 + a3) + xwv;
        gate_lds[tid] = (gtype == 2) ? tanhf(g) : 1.0f / (1.0f + expf(-g));
        __syncthreads();
        if (tid < HD) {
            const float gi = gate_lds[tid];
            const float gf = gate_lds[HD + tid];
            const float gg = gate_lds[2 * HD + tid];
            const float go = gate_lds[3 * HD + tid];
            c = gf * c + gi * gg;
            const float h = go * tanhf(c);
            h_lds[tid] = h;
            stf(&hb_c[t * HD + tid], h);
        }
        t += tstep;
        xwv = xw_pf;
        __syncthreads();
    }
}

// One block per batch element: emissions (parallel over t) into LDS, then
// Viterbi forward on wave 0 (lane = next*8 + prev), then backtrace from LDS.
template<typename HT>
__global__ __launch_bounds__(256, 1)
void viterbi_kernel(const HT* __restrict__ hbuf, const float* __restrict__ W_out,
                    const float* __restrict__ b_out, const float* __restrict__ trans,
                    float* __restrict__ out)
{
    const int b = blockIdx.x;
    const int tid = threadIdx.x;
    __shared__ __align__(16) float wout_lds[NTAG * 256];
    __shared__ __align__(16) float hstage[32 * 256];
    __shared__ __align__(16) float ft_lds[SEQ * 8];
    __shared__ int bptr_lds[SEQ * 8];

    for (int i = tid; i < NTAG * 256; i += 256) wout_lds[i] = W_out[i];
    const HT* __restrict__ HF = hbuf + (size_t)b * (SEQ * HD);
    const HT* __restrict__ HB = hbuf + (size_t)(BSZ + b) * (SEQ * HD);
    __syncthreads();

    // ---- emissions: ft[t][k] = [hf;hb] . W_out[k] + b_out[k] ----
    for (int c0 = 0; c0 < SEQ; c0 += 32) {
        for (int i = tid; i < 32 * 256; i += 256) {
            const int tl = i >> 8;
            const int u = i & 255;
            hstage[i] = (u < HD) ? ldf(&HF[(c0 + tl) * HD + u])
                                 : ldf(&HB[(c0 + tl) * HD + (u - HD)]);
        }
        __syncthreads();
        {
            const int tl = tid >> 3;          // 0..31
            const int k = tid & 7;            // 0..7 (7 = pad, zeroed)
            float v = 0.0f;
            if (k < NTAG) {
                const float4* hv = (const float4*)(hstage + tl * 256);
                const float4* wv = (const float4*)(wout_lds + k * 256);
                float a0 = 0.f, a1 = 0.f, a2 = 0.f, a3 = 0.f;
                #pragma unroll
                for (int q = 0; q < 64; ++q) {
                    const float4 h4 = hv[q], w4 = wv[q];
                    a0 += h4.x * w4.x; a1 += h4.y * w4.y;
                    a2 += h4.z * w4.z; a3 += h4.w * w4.w;
                }
                v = (a0 + a1) + (a2 + a3) + b_out[k];
            }
            ft_lds[(c0 + tl) * 8 + k] = v;
        }
        __syncthreads();
    }

    // ---- Viterbi forward + backtrace, single wave ----
    if (tid < 64) {
        const int next = tid >> 3;
        const int prev = tid & 7;
        const bool pv = (prev < NTAG);
        const bool nv = (next < NTAG);
        const float trv = (pv && nv) ? trans[next * NTAG + prev] : -3.0e38f;
        float fvp = pv ? ((prev == BOSX) ? 0.0f : NEGC) : -3.0e38f;
        for (int t = 0; t < SEQ; ++t) {
            float m = fvp + trv;
            int am = prev;
            #pragma unroll
            for (int off = 1; off < 8; off <<= 1) {      // first-max-index semantics
                const float om = __shfl_xor(m, off);
                const int oa = __shfl_xor(am, off);
                if (om > m || (om == m && oa < am)) { m = om; am = oa; }
            }
            const float fvnew = m + ft_lds[t * 8 + next];
            if (prev == 0) bptr_lds[t * 8 + next] = am;
            fvp = __shfl(fvnew, prev << 3);              // fv_new[my prev] lives in group prev
            if (!pv) fvp = -3.0e38f;
        }
        // terminal = fv + trans[EOS]; argmax (first-index) over prev, lanes 0..7
        float term = pv ? (fvp + trans[EOSX * NTAG + prev]) : -3.0e38f;
        int am = prev;
        #pragma unroll
        for (int off = 1; off < 8; off <<= 1) {
            const float om = __shfl_xor(term, off);
            const int oa = __shfl_xor(am, off);
            if (om > term || (om == term && oa < am)) { term = om; am = oa; }
        }
        if (tid == 0) {
            out[b] = term;                               // path_score
            int cur = am;
            for (int t = SEQ - 1; t >= 0; --t) {
                out[BSZ + t * BSZ + b] = (float)cur;     // tag_seq[t,b] as float
                cur = bptr_lds[t * 8 + cur];
            }
        }
    }
}

extern "C" void kernel_launch(void* const* d_in, const int* in_sizes, int n_in,
                              void* d_out, int out_size, void* d_ws, size_t ws_size,
                              hipStream_t stream)
{
    const int*   sen   = (const int*)d_in[0];
    const float* emb   = (const float*)d_in[1];
    const float* Wih_f = (const float*)d_in[2];
    const float* Whh_f = (const float*)d_in[3];
    const float* b_f   = (const float*)d_in[4];
    const float* Wih_b = (const float*)d_in[5];
    const float* Whh_b = (const float*)d_in[6];
    const float* b_b   = (const float*)d_in[7];
    const float* W_out = (const float*)d_in[8];
    const float* b_out = (const float*)d_in[9];
    const float* trans = (const float*)d_in[10];
    float* out = (float*)d_out;

    char* ws = (char*)d_ws;
    const size_t xw_elems = (size_t)2 * BSZ * SEQ * H4;   // 67,108,864
    const size_t h_elems  = (size_t)2 * BSZ * SEQ * HD;   // 16,777,216

    if (ws_size >= xw_elems * 4 + h_elems * 4) {
        float* xw = (float*)ws;
        float* hb = (float*)(ws + xw_elems * 4);
        lstm_chain_kernel<float, float><<<dim3(2 * BSZ), dim3(512), 0, stream>>>(
            sen, emb, Wih_f, Whh_f, b_f, Wih_b, Whh_b, b_b, xw, hb);
        viterbi_kernel<float><<<dim3(BSZ), dim3(256), 0, stream>>>(hb, W_out, b_out, trans, out);
    } else if (ws_size >= xw_elems * 2 + h_elems * 4) {
        __hip_bfloat16* xw = (__hip_bfloat16*)ws;
        float* hb = (float*)(ws + xw_elems * 2);
        lstm_chain_kernel<__hip_bfloat16, float><<<dim3(2 * BSZ), dim3(512), 0, stream>>>(
            sen, emb, Wih_f, Whh_f, b_f, Wih_b, Whh_b, b_b, xw, hb);
        viterbi_kernel<float><<<dim3(BSZ), dim3(256), 0, stream>>>(hb, W_out, b_out, trans, out);
    } else {
        __hip_bfloat16* xw = (__hip_bfloat16*)ws;
        __hip_bfloat16* hb = (__hip_bfloat16*)(ws + xw_elems * 2);
        lstm_chain_kernel<__hip_bfloat16, __hip_bfloat16><<<dim3(2 * BSZ), dim3(512), 0, stream>>>(
            sen, emb, Wih_f, Whh_f, b_f, Wih_b, Whh_b, b_b, xw, hb);
        viterbi_kernel<__hip_bfloat16><<<dim3(BSZ), dim3(256), 0, stream>>>(hb, W_out, b_out, trans, out);
    }
}